// Round 2
// baseline (58.039 us; speedup 1.0000x reference)
//
#include <hip/hip_runtime.h>
#include <math.h>

#define NROWS 262144
#define DDIM 64
#define NPROT 512
#define NBLK 512   // 512 rows per block, 8 waves
#define MAGIC 0x5A17C0DEu

typedef __attribute__((ext_vector_type(8))) short short8;
typedef __attribute__((ext_vector_type(4))) float f32x4;

__device__ __forceinline__ unsigned short f2bf(float f) {
    union { float f; unsigned u; } c; c.f = f;
    unsigned r = c.u + 0x7FFFu + ((c.u >> 16) & 1u);  // RNE
    return (unsigned short)(r >> 16);
}

__device__ __forceinline__ unsigned cvt_pk_bf16(float lo, float hi) {
    unsigned r;
    asm("v_cvt_pk_bf16_f32 %0, %1, %2" : "=v"(r) : "v"(lo), "v"(hi));
    return r;
}

// v = min(v, dpp-permuted v); CTRL compile-time (0xB1 xor1, 0x4E xor2,
// 0x141 row_half_mirror = xor4, 0x140 row_mirror = xor8) — within 16-lane rows
template <int CTRL>
__device__ __forceinline__ float dpp_min(float v) {
    int s = __builtin_amdgcn_update_dpp(__float_as_int(v), __float_as_int(v),
                                        CTRL, 0xF, 0xF, true);
    return fminf(v, __int_as_float(s));
}

// ---- pre-kernel: protos -> bf16(-2p); slot = jj*64 + t*16 + col ----
// p = (jj + 8t)*16 + col, class = jj*16 + col (t-free).
__global__ __launch_bounds__(64) void glvq_prep(
    const float* __restrict__ protos,
    float* __restrict__ psq_ws,
    uint4* __restrict__ pb_ws)
{
    const int p = blockIdx.x * 64 + threadIdx.x;  // 8 blocks x 64
    const int jj = (p >> 4) & 7, col = p & 15, t = p >> 7;
    const int slot = jj * 64 + t * 16 + col;
    const float* pr = protos + p * DDIM;
    float sq = 0.f;
#pragma unroll
    for (int c = 0; c < 8; ++c) {
        float4 v0 = *reinterpret_cast<const float4*>(pr + c * 8);
        float4 v1 = *reinterpret_cast<const float4*>(pr + c * 8 + 4);
        sq += v0.x * v0.x + v0.y * v0.y + v0.z * v0.z + v0.w * v0.w +
              v1.x * v1.x + v1.y * v1.y + v1.z * v1.z + v1.w * v1.w;
        union { unsigned short s[8]; uint4 u; } pk;
        pk.s[0] = f2bf(-2.f * v0.x); pk.s[1] = f2bf(-2.f * v0.y);
        pk.s[2] = f2bf(-2.f * v0.z); pk.s[3] = f2bf(-2.f * v0.w);
        pk.s[4] = f2bf(-2.f * v1.x); pk.s[5] = f2bf(-2.f * v1.y);
        pk.s[6] = f2bf(-2.f * v1.z); pk.s[7] = f2bf(-2.f * v1.w);
        pb_ws[(slot * 8 + c) ^ (slot & 7)] = pk.u;
    }
    // psq layout: [jj (8)][col (16)][t (4)]
    psq_ws[jj * 64 + col * 4 + t] = sq;
}

// ---- main kernel: 8 waves x 64 rows, all protos resident, flag-tail ----
__global__ __launch_bounds__(512, 4) void glvq_main(
    const float* __restrict__ x,
    const int* __restrict__ y,
    const float* __restrict__ psq_ws,
    const uint4* __restrict__ pb_ws,
    float* __restrict__ partial,
    unsigned* __restrict__ flags,
    float* __restrict__ out)
{
    __shared__ uint4 s_pb[NPROT * 8];   // 64 KB: all bf16(-2p) protos, swizzled
    __shared__ float s_psq[NPROT];      // 2 KB, [jj][col][t]
    __shared__ float s_xsq[8][64];      // 2 KB
    __shared__ int   s_y[512];          // 2 KB
    __shared__ float s_red[8];

    const int tid = threadIdx.x;
    const int lane = tid & 63, w = tid >> 6;       // w in 0..7
    const int g = lane >> 4, col = lane & 15;
    const int row0 = blockIdx.x * 512;

    // x loads first (HBM latency-critical): row = row0 + w*64 + rt*16 + col
    float4 raw[16];
    {
        const float* xb = x + (size_t)(row0 + w * 64 + col) * DDIM;
#pragma unroll
        for (int rt = 0; rt < 4; ++rt)
#pragma unroll
            for (int kk = 0; kk < 2; ++kk) {
                raw[rt * 4 + kk * 2 + 0] =
                    *reinterpret_cast<const float4*>(xb + rt * 1024 + kk * 32 + g * 8);
                raw[rt * 4 + kk * 2 + 1] =
                    *reinterpret_cast<const float4*>(xb + rt * 1024 + kk * 32 + g * 8 + 4);
            }
    }

    // stage all protos + psq + y (ws is L2-resident); 128 B/thread
#pragma unroll
    for (int i = 0; i < 8; ++i) s_pb[tid + 512 * i] = pb_ws[tid + 512 * i];
    s_psq[tid] = psq_ws[tid];
    s_y[tid] = y[row0 + tid];

    // convert to A fragments + row norms
    short8 afrag[4][2];
#pragma unroll
    for (int rt = 0; rt < 4; ++rt) {
        float part = 0.f;
#pragma unroll
        for (int kk = 0; kk < 2; ++kk) {
            float4 a0 = raw[rt * 4 + kk * 2 + 0];
            float4 a1 = raw[rt * 4 + kk * 2 + 1];
            part += a0.x * a0.x + a0.y * a0.y + a0.z * a0.z + a0.w * a0.w +
                    a1.x * a1.x + a1.y * a1.y + a1.z * a1.z + a1.w * a1.w;
            union { unsigned u[4]; short8 s; } pk;
            pk.u[0] = cvt_pk_bf16(a0.x, a0.y);
            pk.u[1] = cvt_pk_bf16(a0.z, a0.w);
            pk.u[2] = cvt_pk_bf16(a1.x, a1.y);
            pk.u[3] = cvt_pk_bf16(a1.z, a1.w);
            afrag[rt][kk] = pk.s;
        }
        part += __shfl_xor(part, 16);
        part += __shfl_xor(part, 32);
        if (g == 0) s_xsq[w][rt * 16 + col] = part;
    }

    __syncthreads();  // protos/psq/y visible; only barrier before the end

    // corr <=> jcv[rt][r] == jj
    int jcv[4][4];
#pragma unroll
    for (int rt = 0; rt < 4; ++rt)
#pragma unroll
        for (int r = 0; r < 4; ++r) {
            int yv = s_y[w * 64 + rt * 16 + g * 4 + r];
            jcv[rt][r] = ((yv & 15) == col) ? (yv >> 4) : 15;
        }

    float m1[4][4], m2[4][4];
#pragma unroll
    for (int rt = 0; rt < 4; ++rt)
#pragma unroll
        for (int r = 0; r < 4; ++r) { m1[rt][r] = INFINITY; m2[rt][r] = INFINITY; }

    // per-lane constant LDS bases; t offsets fold into ds immediates
    const int sw = (col & 7) << 4;
    const char* s_pb_c = (const char*)s_pb;
    const char* pb0 = s_pb_c + col * 128 + ((g * 16) ^ sw);
    const char* pb1 = s_pb_c + col * 128 + ((g * 16 + 64) ^ sw);
    const char* pqc = (const char*)s_psq + col * 16;

#pragma unroll
    for (int jj = 0; jj < 8; ++jj) {
        // de-convoy: each of the 8 waves walks the proto tiles rotated
        const int jjr = (jj + w) & 7;
        const int bj = jjr * 8192;
        const f32x4 psqv = *reinterpret_cast<const f32x4*>(pqc + jjr * 256);
        float vmin[4][4];
#pragma unroll
        for (int rt = 0; rt < 4; ++rt)
#pragma unroll
            for (int r = 0; r < 4; ++r) vmin[rt][r] = INFINITY;
#pragma unroll
        for (int t = 0; t < 4; ++t) {
            short8 b0 = *reinterpret_cast<const short8*>(pb0 + bj + t * 2048);
            short8 b1 = *reinterpret_cast<const short8*>(pb1 + bj + t * 2048);
            const float sd = psqv[t];
#pragma unroll
            for (int rt = 0; rt < 4; ++rt) {
                f32x4 a = {sd, sd, sd, sd};  // seed acc with ||p||^2
                a = __builtin_amdgcn_mfma_f32_16x16x32_bf16(afrag[rt][0], b0, a, 0, 0, 0);
                a = __builtin_amdgcn_mfma_f32_16x16x32_bf16(afrag[rt][1], b1, a, 0, 0, 0);
#pragma unroll
                for (int r = 0; r < 4; ++r)
                    vmin[rt][r] = fminf(vmin[rt][r], a[r]);
            }
        }
#pragma unroll
        for (int rt = 0; rt < 4; ++rt)
#pragma unroll
            for (int r = 0; r < 4; ++r) {
                float v = vmin[rt][r];
                bool corr = (jcv[rt][r] == jjr);
                m1[rt][r] = corr ? v : m1[rt][r];                  // hits exactly once
                m2[rt][r] = corr ? m2[rt][r] : fminf(m2[rt][r], v);
            }
    }

    // epilogue: DPP min over 16 proto-columns, mu/sigmoid
    float lsum = 0.f;
#pragma unroll
    for (int rt = 0; rt < 4; ++rt)
#pragma unroll
        for (int r = 0; r < 4; ++r) {
            float a1 = m1[rt][r], a2 = m2[rt][r];
            a1 = dpp_min<0xB1>(a1);  a2 = dpp_min<0xB1>(a2);   // xor 1
            a1 = dpp_min<0x4E>(a1);  a2 = dpp_min<0x4E>(a2);   // xor 2
            a1 = dpp_min<0x141>(a1); a2 = dpp_min<0x141>(a2);  // xor 4
            a1 = dpp_min<0x140>(a1); a2 = dpp_min<0x140>(a2);  // xor 8
            float xsq = s_xsq[w][rt * 16 + g * 4 + r];
            float d1 = xsq + a1, d2 = xsq + a2;
            float mu = (d1 - d2) / (d1 + d2 + 1e-9f);
            float sig = 1.f / (1.f + __expf(-mu));
            lsum += (col == 0) ? sig : 0.f;
        }
#pragma unroll
    for (int mk = 1; mk <= 32; mk <<= 1) lsum += __shfl_xor(lsum, mk);
    if (lane == 0) s_red[w] = lsum;
    __syncthreads();

    // publish partial: agent-scope store + release flag (ws is poisoned, so
    // readiness is signalled by MAGIC; no pre-zeroed counter needed)
    if (tid == 0) {
        float bsum = ((s_red[0] + s_red[1]) + (s_red[2] + s_red[3])) +
                     ((s_red[4] + s_red[5]) + (s_red[6] + s_red[7]));
        __hip_atomic_store(&partial[blockIdx.x], bsum,
                           __ATOMIC_RELAXED, __HIP_MEMORY_SCOPE_AGENT);
        __hip_atomic_store(&flags[blockIdx.x], MAGIC,
                           __ATOMIC_RELEASE, __HIP_MEMORY_SCOPE_AGENT);
    }

    // block 0 polls all flags, then reduces (replaces finalize kernel).
    // Polling never blocks producers: other resident blocks keep draining.
    if (blockIdx.x == 0) {
        float acc = 0.f;
        for (int i = tid; i < NBLK; i += 512) {
            while (__hip_atomic_load(&flags[i], __ATOMIC_ACQUIRE,
                                     __HIP_MEMORY_SCOPE_AGENT) != MAGIC)
                __builtin_amdgcn_s_sleep(2);
            acc += __hip_atomic_load(&partial[i], __ATOMIC_RELAXED,
                                     __HIP_MEMORY_SCOPE_AGENT);
        }
        __syncthreads();  // s_red reads above are done; safe to reuse
#pragma unroll
        for (int mk = 1; mk <= 32; mk <<= 1) acc += __shfl_xor(acc, mk);
        if (lane == 0) s_red[w] = acc;
        __syncthreads();
        if (tid == 0)
            out[0] = (((s_red[0] + s_red[1]) + (s_red[2] + s_red[3])) +
                      ((s_red[4] + s_red[5]) + (s_red[6] + s_red[7]))) *
                     (1.0f / (float)NROWS);
    }
}

extern "C" void kernel_launch(void* const* d_in, const int* in_sizes, int n_in,
                              void* d_out, int out_size, void* d_ws, size_t ws_size,
                              hipStream_t stream) {
    const float* x = (const float*)d_in[0];
    const float* protos = (const float*)d_in[1];
    const int* y = (const int*)d_in[2];
    float* out = (float*)d_out;

    // ws layout: [0..2K) partials | [2K..4K) flags | [4K..6K) psq | [8K..72K) bf16 protos
    float* partial = (float*)d_ws;
    unsigned* flags = (unsigned*)((char*)d_ws + 2048);
    float* psq_ws = (float*)((char*)d_ws + 4096);
    uint4* pb_ws = (uint4*)((char*)d_ws + 8192);

    glvq_prep<<<8, 64, 0, stream>>>(protos, psq_ws, pb_ws);
    glvq_main<<<NBLK, 512, 0, stream>>>(x, y, psq_ws, pb_ws, partial, flags, out);
}

// Round 3
// 44.439 us; speedup vs baseline: 1.3060x; 1.3060x over previous
//
#include <hip/hip_runtime.h>
#include <math.h>

#define NROWS 262144
#define DDIM 64
#define NPROT 512
#define NBLK 512   // 512 rows per block, 8 waves; grid 512 = 2 blocks/CU, one round
#define MAGIC 0x5A17C0DEu

typedef __attribute__((ext_vector_type(8))) short short8;
typedef __attribute__((ext_vector_type(4))) float f32x4;

__device__ __forceinline__ unsigned short f2bf(float f) {
    union { float f; unsigned u; } c; c.f = f;
    unsigned r = c.u + 0x7FFFu + ((c.u >> 16) & 1u);  // RNE
    return (unsigned short)(r >> 16);
}

__device__ __forceinline__ unsigned cvt_pk_bf16(float lo, float hi) {
    unsigned r;
    asm("v_cvt_pk_bf16_f32 %0, %1, %2" : "=v"(r) : "v"(lo), "v"(hi));
    return r;
}

// v = min(v, dpp-permuted v); CTRL compile-time (0xB1 xor1, 0x4E xor2,
// 0x141 row_half_mirror = xor4, 0x140 row_mirror = xor8) — within 16-lane rows
template <int CTRL>
__device__ __forceinline__ float dpp_min(float v) {
    int s = __builtin_amdgcn_update_dpp(__float_as_int(v), __float_as_int(v),
                                        CTRL, 0xF, 0xF, true);
    return fminf(v, __int_as_float(s));
}

// ---- pre-kernel: protos -> bf16(-2p); slot = jj*64 + t*16 + col ----
// p = (jj + 8t)*16 + col, class = jj*16 + col (t-free).
__global__ __launch_bounds__(64) void glvq_prep(
    const float* __restrict__ protos,
    float* __restrict__ psq_ws,
    uint4* __restrict__ pb_ws)
{
    const int p = blockIdx.x * 64 + threadIdx.x;  // 8 blocks x 64
    const int jj = (p >> 4) & 7, col = p & 15, t = p >> 7;
    const int slot = jj * 64 + t * 16 + col;
    const float* pr = protos + p * DDIM;
    float sq = 0.f;
#pragma unroll
    for (int c = 0; c < 8; ++c) {
        float4 v0 = *reinterpret_cast<const float4*>(pr + c * 8);
        float4 v1 = *reinterpret_cast<const float4*>(pr + c * 8 + 4);
        sq += v0.x * v0.x + v0.y * v0.y + v0.z * v0.z + v0.w * v0.w +
              v1.x * v1.x + v1.y * v1.y + v1.z * v1.z + v1.w * v1.w;
        union { unsigned short s[8]; uint4 u; } pk;
        pk.s[0] = f2bf(-2.f * v0.x); pk.s[1] = f2bf(-2.f * v0.y);
        pk.s[2] = f2bf(-2.f * v0.z); pk.s[3] = f2bf(-2.f * v0.w);
        pk.s[4] = f2bf(-2.f * v1.x); pk.s[5] = f2bf(-2.f * v1.y);
        pk.s[6] = f2bf(-2.f * v1.z); pk.s[7] = f2bf(-2.f * v1.w);
        pb_ws[(slot * 8 + c) ^ (slot & 7)] = pk.u;
    }
    // psq layout: [jj (8)][col (16)][t (4)]
    psq_ws[jj * 64 + col * 4 + t] = sq;
}

// ---- main kernel: 8 waves x 64 rows, all protos resident, flag-tail ----
// __launch_bounds__ 2nd arg behaves as BLOCKS/CU on this toolchain (round-2
// evidence: (512,4) -> 64-VGPR cap = 32 waves/CU). (512,2) -> 16 waves/CU
// -> 128-VGPR cap: fits ~115 live regs, no spill, 4 waves/SIMD.
__global__ __launch_bounds__(512, 2) void glvq_main(
    const float* __restrict__ x,
    const int* __restrict__ y,
    const float* __restrict__ psq_ws,
    const uint4* __restrict__ pb_ws,
    float* __restrict__ partial,
    unsigned* __restrict__ flags,
    float* __restrict__ out)
{
    __shared__ uint4 s_pb[NPROT * 8];   // 64 KB: all bf16(-2p) protos, swizzled
    __shared__ float s_psq[NPROT];      // 2 KB, [jj][col][t]
    __shared__ float s_xsq[8][64];      // 2 KB
    __shared__ int   s_y[512];          // 2 KB
    __shared__ float s_red[8];

    const int tid = threadIdx.x;
    const int lane = tid & 63, w = tid >> 6;       // w in 0..7
    const int g = lane >> 4, col = lane & 15;
    const int row0 = blockIdx.x * 512;

    // x loads first (HBM latency-critical): row = row0 + w*64 + rt*16 + col
    float4 raw[16];
    {
        const float* xb = x + (size_t)(row0 + w * 64 + col) * DDIM;
#pragma unroll
        for (int rt = 0; rt < 4; ++rt)
#pragma unroll
            for (int kk = 0; kk < 2; ++kk) {
                raw[rt * 4 + kk * 2 + 0] =
                    *reinterpret_cast<const float4*>(xb + rt * 1024 + kk * 32 + g * 8);
                raw[rt * 4 + kk * 2 + 1] =
                    *reinterpret_cast<const float4*>(xb + rt * 1024 + kk * 32 + g * 8 + 4);
            }
    }

    // stage all protos + psq + y (ws is L2-resident); 128 B/thread
#pragma unroll
    for (int i = 0; i < 8; ++i) s_pb[tid + 512 * i] = pb_ws[tid + 512 * i];
    s_psq[tid] = psq_ws[tid];
    s_y[tid] = y[row0 + tid];

    // convert to A fragments + row norms
    short8 afrag[4][2];
#pragma unroll
    for (int rt = 0; rt < 4; ++rt) {
        float part = 0.f;
#pragma unroll
        for (int kk = 0; kk < 2; ++kk) {
            float4 a0 = raw[rt * 4 + kk * 2 + 0];
            float4 a1 = raw[rt * 4 + kk * 2 + 1];
            part += a0.x * a0.x + a0.y * a0.y + a0.z * a0.z + a0.w * a0.w +
                    a1.x * a1.x + a1.y * a1.y + a1.z * a1.z + a1.w * a1.w;
            union { unsigned u[4]; short8 s; } pk;
            pk.u[0] = cvt_pk_bf16(a0.x, a0.y);
            pk.u[1] = cvt_pk_bf16(a0.z, a0.w);
            pk.u[2] = cvt_pk_bf16(a1.x, a1.y);
            pk.u[3] = cvt_pk_bf16(a1.z, a1.w);
            afrag[rt][kk] = pk.s;
        }
        part += __shfl_xor(part, 16);
        part += __shfl_xor(part, 32);
        if (g == 0) s_xsq[w][rt * 16 + col] = part;
    }

    __syncthreads();  // protos/psq/y visible; only barrier before the end

    // corr <=> jcv[rt][r] == jj
    int jcv[4][4];
#pragma unroll
    for (int rt = 0; rt < 4; ++rt)
#pragma unroll
        for (int r = 0; r < 4; ++r) {
            int yv = s_y[w * 64 + rt * 16 + g * 4 + r];
            jcv[rt][r] = ((yv & 15) == col) ? (yv >> 4) : 15;
        }

    float m1[4][4], m2[4][4];
#pragma unroll
    for (int rt = 0; rt < 4; ++rt)
#pragma unroll
        for (int r = 0; r < 4; ++r) { m1[rt][r] = INFINITY; m2[rt][r] = INFINITY; }

    // per-lane constant LDS bases; t offsets fold into ds immediates
    const int sw = (col & 7) << 4;
    const char* s_pb_c = (const char*)s_pb;
    const char* pb0 = s_pb_c + col * 128 + ((g * 16) ^ sw);
    const char* pb1 = s_pb_c + col * 128 + ((g * 16 + 64) ^ sw);
    const char* pqc = (const char*)s_psq + col * 16;

#pragma unroll
    for (int jj = 0; jj < 8; ++jj) {
        // de-convoy: each of the 8 waves walks the proto tiles rotated
        const int jjr = (jj + w) & 7;
        const int bj = jjr * 8192;
        const f32x4 psqv = *reinterpret_cast<const f32x4*>(pqc + jjr * 256);
        float vmin[4][4];
#pragma unroll
        for (int rt = 0; rt < 4; ++rt)
#pragma unroll
            for (int r = 0; r < 4; ++r) vmin[rt][r] = INFINITY;
#pragma unroll
        for (int t = 0; t < 4; ++t) {
            short8 b0 = *reinterpret_cast<const short8*>(pb0 + bj + t * 2048);
            short8 b1 = *reinterpret_cast<const short8*>(pb1 + bj + t * 2048);
            const float sd = psqv[t];
#pragma unroll
            for (int rt = 0; rt < 4; ++rt) {
                f32x4 a = {sd, sd, sd, sd};  // seed acc with ||p||^2
                a = __builtin_amdgcn_mfma_f32_16x16x32_bf16(afrag[rt][0], b0, a, 0, 0, 0);
                a = __builtin_amdgcn_mfma_f32_16x16x32_bf16(afrag[rt][1], b1, a, 0, 0, 0);
#pragma unroll
                for (int r = 0; r < 4; ++r)
                    vmin[rt][r] = fminf(vmin[rt][r], a[r]);
            }
        }
#pragma unroll
        for (int rt = 0; rt < 4; ++rt)
#pragma unroll
            for (int r = 0; r < 4; ++r) {
                float v = vmin[rt][r];
                bool corr = (jcv[rt][r] == jjr);
                m1[rt][r] = corr ? v : m1[rt][r];                  // hits exactly once
                m2[rt][r] = corr ? m2[rt][r] : fminf(m2[rt][r], v);
            }
    }

    // epilogue: DPP min over 16 proto-columns, mu/sigmoid
    float lsum = 0.f;
#pragma unroll
    for (int rt = 0; rt < 4; ++rt)
#pragma unroll
        for (int r = 0; r < 4; ++r) {
            float a1 = m1[rt][r], a2 = m2[rt][r];
            a1 = dpp_min<0xB1>(a1);  a2 = dpp_min<0xB1>(a2);   // xor 1
            a1 = dpp_min<0x4E>(a1);  a2 = dpp_min<0x4E>(a2);   // xor 2
            a1 = dpp_min<0x141>(a1); a2 = dpp_min<0x141>(a2);  // xor 4
            a1 = dpp_min<0x140>(a1); a2 = dpp_min<0x140>(a2);  // xor 8
            float xsq = s_xsq[w][rt * 16 + g * 4 + r];
            float d1 = xsq + a1, d2 = xsq + a2;
            float mu = (d1 - d2) / (d1 + d2 + 1e-9f);
            float sig = 1.f / (1.f + __expf(-mu));
            lsum += (col == 0) ? sig : 0.f;
        }
#pragma unroll
    for (int mk = 1; mk <= 32; mk <<= 1) lsum += __shfl_xor(lsum, mk);
    if (lane == 0) s_red[w] = lsum;
    __syncthreads();

    // publish partial: agent-scope store + release flag (ws is poisoned, so
    // readiness is signalled by MAGIC; no pre-zeroed counter needed)
    if (tid == 0) {
        float bsum = ((s_red[0] + s_red[1]) + (s_red[2] + s_red[3])) +
                     ((s_red[4] + s_red[5]) + (s_red[6] + s_red[7]));
        __hip_atomic_store(&partial[blockIdx.x], bsum,
                           __ATOMIC_RELAXED, __HIP_MEMORY_SCOPE_AGENT);
        __hip_atomic_store(&flags[blockIdx.x], MAGIC,
                           __ATOMIC_RELEASE, __HIP_MEMORY_SCOPE_AGENT);
    }

    // block 0 polls all flags, then reduces (replaces finalize kernel).
    // Grid 512 = fully co-resident (2 blocks/CU), so producers always progress.
    if (blockIdx.x == 0) {
        float acc = 0.f;
        for (int i = tid; i < NBLK; i += 512) {
            while (__hip_atomic_load(&flags[i], __ATOMIC_ACQUIRE,
                                     __HIP_MEMORY_SCOPE_AGENT) != MAGIC)
                __builtin_amdgcn_s_sleep(2);
            acc += __hip_atomic_load(&partial[i], __ATOMIC_RELAXED,
                                     __HIP_MEMORY_SCOPE_AGENT);
        }
        __syncthreads();  // s_red reads above are done; safe to reuse
#pragma unroll
        for (int mk = 1; mk <= 32; mk <<= 1) acc += __shfl_xor(acc, mk);
        if (lane == 0) s_red[w] = acc;
        __syncthreads();
        if (tid == 0)
            out[0] = (((s_red[0] + s_red[1]) + (s_red[2] + s_red[3])) +
                      ((s_red[4] + s_red[5]) + (s_red[6] + s_red[7]))) *
                     (1.0f / (float)NROWS);
    }
}

extern "C" void kernel_launch(void* const* d_in, const int* in_sizes, int n_in,
                              void* d_out, int out_size, void* d_ws, size_t ws_size,
                              hipStream_t stream) {
    const float* x = (const float*)d_in[0];
    const float* protos = (const float*)d_in[1];
    const int* y = (const int*)d_in[2];
    float* out = (float*)d_out;

    // ws layout: [0..2K) partials | [2K..4K) flags | [4K..6K) psq | [8K..72K) bf16 protos
    float* partial = (float*)d_ws;
    unsigned* flags = (unsigned*)((char*)d_ws + 2048);
    float* psq_ws = (float*)((char*)d_ws + 4096);
    uint4* pb_ws = (uint4*)((char*)d_ws + 8192);

    glvq_prep<<<8, 64, 0, stream>>>(protos, psq_ws, pb_ws);
    glvq_main<<<NBLK, 512, 0, stream>>>(x, y, psq_ws, pb_ws, partial, flags, out);
}